// Round 4
// baseline (314.510 us; speedup 1.0000x reference)
//
#include <hip/hip_runtime.h>
#include <hip/hip_bf16.h>

#define B_DIM 16384
#define C_DIM 512
#define F_DIM 1024
#define LOG2E 1.4426950408889634f
#define ROWS_PER_BLOCK 8                    // 2 rows per wave, 4 waves/block
#define NBLOCKS (B_DIM / ROWS_PER_BLOCK)    // 2048 blocks = machine capacity

typedef float f32x4 __attribute__((ext_vector_type(4)));

// d_ws layout:
//   [0]   u32 ticket   (memset to 0 per call)
//   [1]   u32 done     (memset to 0 per call)
//   +256B f32 factor2[C_DIM]
//
// Fused kernel: first 128 blocks TO ARRIVE (by ticket — deadlock-free under
// any dispatch order) compute the per-class Weibull factor; all blocks
// prefetch their logits rows first so the 64 MB stream overlaps the 2 MB
// factor computation. Producers publish with agent-scope (cross-XCD) stores.
__global__ __launch_bounds__(256) void openmax_fused(
    const float* __restrict__ logits,      // (B,C)
    const float* __restrict__ features,    // (B,F) — row 0 only
    const float* __restrict__ mean_vecs,   // (C,F)
    const float* __restrict__ wparams,     // (C,3)
    unsigned int* __restrict__ ctl,        // [0]=ticket, [1]=done
    float* __restrict__ factor2,           // (C,) = (1-w^10)*log2e
    float* __restrict__ out)               // (B,C)
{
    const int wid  = threadIdx.x >> 6;
    const int lane = threadIdx.x & 63;

    // ---- block ticket: first 128 arrivals are producers ----
    __shared__ unsigned int s_tk;
    if (threadIdx.x == 0) s_tk = atomicAdd(&ctl[0], 1u);
    __syncthreads();
    const unsigned int tk = s_tk;

    // ---- issue this wave's logits loads NOW (overlap with factor phase) ----
    const size_t row0 = (size_t)blockIdx.x * ROWS_PER_BLOCK + wid * 2;
    const f32x4* lr0 = (const f32x4*)(logits + row0 * C_DIM);
    const f32x4* lr1 = (const f32x4*)(logits + (row0 + 1) * C_DIM);
    const f32x4 a0 = lr0[lane];
    const f32x4 a1 = lr0[64 + lane];
    const f32x4 b0 = lr1[lane];
    const f32x4 b1 = lr1[64 + lane];

    // ---- producer phase: one class per wave, 128 blocks x 4 waves = 512 ----
    if (tk < (unsigned)(C_DIM / 4)) {
        const int c = (int)tk * 4 + wid;
        const f32x4* mv = (const f32x4*)(mean_vecs + (size_t)c * F_DIM);
        const f32x4* ft = (const f32x4*)features;
        float s = 0.0f;
#pragma unroll
        for (int j = 0; j < 4; ++j) {
            const f32x4 a = ft[lane + j * 64];
            const f32x4 b = mv[lane + j * 64];
            const float dx = a.x - b.x, dy = a.y - b.y;
            const float dz = a.z - b.z, dw = a.w - b.w;
            s = fmaf(dx, dx, s); s = fmaf(dy, dy, s);
            s = fmaf(dz, dz, s); s = fmaf(dw, dw, s);
        }
#pragma unroll
        for (int off = 32; off > 0; off >>= 1)
            s += __shfl_xor(s, off, 64);

        if (lane == 0) {
            const float d0  = sqrtf(s);
            const float shp = wparams[c * 3 + 0];
            const float loc = wparams[c * 3 + 1];
            const float scl = wparams[c * 3 + 2];
            const float z   = fmaxf((d0 - loc) / scl, 0.0f);
            const float w   = 1.0f - expf(-powf(z, shp));
            const float w2  = w * w;
            const float w4  = w2 * w2;
            const float w8  = w4 * w4;
            const float val = (1.0f - w8 * w2) * LOG2E;   // (1-w^10)*log2e
            __hip_atomic_store(&factor2[c], val,
                               __ATOMIC_RELEASE, __HIP_MEMORY_SCOPE_AGENT);
            __hip_atomic_fetch_add(&ctl[1], 1u,
                                   __ATOMIC_ACQ_REL, __HIP_MEMORY_SCOPE_AGENT);
        }
    }

    // ---- wait until all 512 factors are published ----
    while (__hip_atomic_load(&ctl[1], __ATOMIC_ACQUIRE,
                             __HIP_MEMORY_SCOPE_AGENT) < (unsigned)C_DIM)
        __builtin_amdgcn_s_sleep(8);

    // ---- read factors (agent scope: bypass possibly-stale local caches) ----
    float f[8];
#pragma unroll
    for (int j = 0; j < 4; ++j) {
        f[j]     = __hip_atomic_load(&factor2[lane * 4 + j],
                                     __ATOMIC_RELAXED, __HIP_MEMORY_SCOPE_AGENT);
        f[4 + j] = __hip_atomic_load(&factor2[256 + lane * 4 + j],
                                     __ATOMIC_RELAXED, __HIP_MEMORY_SCOPE_AGENT);
    }

    // ---- row A softmax (log2-domain, no max subtraction: |s| <= ~8) ----
    float eA[8], eB[8];
    eA[0] = __builtin_amdgcn_exp2f(a0.x * f[0]);
    eA[1] = __builtin_amdgcn_exp2f(a0.y * f[1]);
    eA[2] = __builtin_amdgcn_exp2f(a0.z * f[2]);
    eA[3] = __builtin_amdgcn_exp2f(a0.w * f[3]);
    eA[4] = __builtin_amdgcn_exp2f(a1.x * f[4]);
    eA[5] = __builtin_amdgcn_exp2f(a1.y * f[5]);
    eA[6] = __builtin_amdgcn_exp2f(a1.z * f[6]);
    eA[7] = __builtin_amdgcn_exp2f(a1.w * f[7]);
    eB[0] = __builtin_amdgcn_exp2f(b0.x * f[0]);
    eB[1] = __builtin_amdgcn_exp2f(b0.y * f[1]);
    eB[2] = __builtin_amdgcn_exp2f(b0.z * f[2]);
    eB[3] = __builtin_amdgcn_exp2f(b0.w * f[3]);
    eB[4] = __builtin_amdgcn_exp2f(b1.x * f[4]);
    eB[5] = __builtin_amdgcn_exp2f(b1.y * f[5]);
    eB[6] = __builtin_amdgcn_exp2f(b1.z * f[6]);
    eB[7] = __builtin_amdgcn_exp2f(b1.w * f[7]);

    float sA = ((eA[0]+eA[1]) + (eA[2]+eA[3])) + ((eA[4]+eA[5]) + (eA[6]+eA[7]));
    float sB = ((eB[0]+eB[1]) + (eB[2]+eB[3])) + ((eB[4]+eB[5]) + (eB[6]+eB[7]));
    // two independent reduce chains, interleaved for ILP
#pragma unroll
    for (int off = 32; off > 0; off >>= 1) {
        sA += __shfl_xor(sA, off, 64);
        sB += __shfl_xor(sB, off, 64);
    }
    const float invA = __builtin_amdgcn_rcpf(sA);
    const float invB = __builtin_amdgcn_rcpf(sB);

    f32x4 oA0, oA1, oB0, oB1;
    oA0.x = eA[0]*invA; oA0.y = eA[1]*invA; oA0.z = eA[2]*invA; oA0.w = eA[3]*invA;
    oA1.x = eA[4]*invA; oA1.y = eA[5]*invA; oA1.z = eA[6]*invA; oA1.w = eA[7]*invA;
    oB0.x = eB[0]*invB; oB0.y = eB[1]*invB; oB0.z = eB[2]*invB; oB0.w = eB[3]*invB;
    oB1.x = eB[4]*invB; oB1.y = eB[5]*invB; oB1.z = eB[6]*invB; oB1.w = eB[7]*invB;

    f32x4* or0 = (f32x4*)(out + row0 * C_DIM);
    f32x4* or1 = (f32x4*)(out + (row0 + 1) * C_DIM);
    or0[lane]      = oA0;
    or0[64 + lane] = oA1;
    or1[lane]      = oB0;
    or1[64 + lane] = oB1;
}

// ---------------------------------------------------------------------------
extern "C" void kernel_launch(void* const* d_in, const int* in_sizes, int n_in,
                              void* d_out, int out_size, void* d_ws, size_t ws_size,
                              hipStream_t stream) {
    const float* logits    = (const float*)d_in[0];   // (B,C)
    const float* features  = (const float*)d_in[1];   // (B,F)
    const float* mean_vecs = (const float*)d_in[2];   // (C,F)
    const float* wparams   = (const float*)d_in[3];   // (C,3)
    float* out = (float*)d_out;

    unsigned int* ctl = (unsigned int*)d_ws;
    float* factor2 = (float*)((char*)d_ws + 256);

    // Per-call reset of ticket+done (8 bytes). Capturable async memset.
    hipMemsetAsync(ctl, 0, 2 * sizeof(unsigned int), stream);

    openmax_fused<<<NBLOCKS, 256, 0, stream>>>(logits, features, mean_vecs,
                                               wparams, ctl, factor2, out);
}

// Round 5
// 20.239 us; speedup vs baseline: 15.5401x; 15.5401x over previous
//
#include <hip/hip_runtime.h>
#include <hip/hip_bf16.h>

#define B_DIM 16384
#define C_DIM 512
#define F_DIM 1024
#define LOG2E 1.4426950408889634f

typedef float f32x4 __attribute__((ext_vector_type(4)));

// ---------------------------------------------------------------------------
// Kernel 1: per-class Weibull factor, pre-scaled by log2(e).
//   d0[c]     = || features[0] - mean_vecs[c] ||_2     (F = 1024)
//   z         = max((d0 - loc)/scale, 0)
//   w         = 1 - exp(-z^shape)
//   factor2[c]= (1 - w^10) * log2(e)
// One 64-lane wave per class (512 waves = 128 blocks x 256 thr).
// ---------------------------------------------------------------------------
__global__ __launch_bounds__(256) void openmax_factor_kernel(
    const float* __restrict__ features,     // (B,F) — only row 0 used
    const float* __restrict__ mean_vecs,    // (C,F)
    const float* __restrict__ wparams,      // (C,3) = shape, loc, scale
    float* __restrict__ factor2)            // (C,)
{
    const int c    = (blockIdx.x * 256 + threadIdx.x) >> 6;  // class = wave id
    const int lane = threadIdx.x & 63;

    const f32x4* mv = (const f32x4*)(mean_vecs + (size_t)c * F_DIM);
    const f32x4* ft = (const f32x4*)features;

    float s = 0.0f;
#pragma unroll
    for (int j = 0; j < 4; ++j) {
        const f32x4 a = ft[lane + j * 64];
        const f32x4 b = mv[lane + j * 64];
        const float dx = a.x - b.x, dy = a.y - b.y;
        const float dz = a.z - b.z, dw = a.w - b.w;
        s = fmaf(dx, dx, s); s = fmaf(dy, dy, s);
        s = fmaf(dz, dz, s); s = fmaf(dw, dw, s);
    }
#pragma unroll
    for (int off = 32; off > 0; off >>= 1)
        s += __shfl_xor(s, off, 64);

    if (lane == 0) {
        const float d0  = sqrtf(s);
        const float shp = wparams[c * 3 + 0];
        const float loc = wparams[c * 3 + 1];
        const float scl = wparams[c * 3 + 2];
        const float z   = fmaxf((d0 - loc) / scl, 0.0f);
        const float w   = 1.0f - expf(-powf(z, shp));
        const float w2  = w * w;
        const float w4  = w2 * w2;
        const float w8  = w4 * w4;
        factor2[c] = (1.0f - w8 * w2) * LOG2E;   // (1 - w^10) * log2e
    }
}

// ---------------------------------------------------------------------------
// Kernel 2: scaled row softmax, log2-domain, no max subtraction.
//   scores bounded (|logits| <= ~5.5, factor in [0,1]) -> 2^x in [2^-8, 2^8],
//   no overflow; matches max-subtracted softmax to ~1e-7.
// TWO rows per wave (4 outstanding 16B loads/lane), 8 rows per 256-thr block,
// 2048 blocks = exactly one resident generation (8 blocks/CU x 256 CU).
// No nontemporal hints: logits/out (32+32 MB) are L3-resident across replays
// (R4 measured FETCH=17.5MB) — keep them cacheable.
// ---------------------------------------------------------------------------
__global__ __launch_bounds__(256) void openmax_softmax_kernel(
    const float* __restrict__ logits,   // (B,C)
    const float* __restrict__ factor2,  // (C,) pre-scaled by log2e
    float* __restrict__ out)            // (B,C)
{
    const int wid  = threadIdx.x >> 6;
    const int lane = threadIdx.x & 63;
    const size_t row0 = ((size_t)blockIdx.x * 4 + wid) * 2;

    const f32x4* lr0 = (const f32x4*)(logits + row0 * C_DIM);
    const f32x4* lr1 = (const f32x4*)(logits + (row0 + 1) * C_DIM);
    const f32x4* frow = (const f32x4*)factor2;

    // 4 independent 16B loads (plus 2 L2-hot factor loads): deep MLP.
    const f32x4 a0 = lr0[lane];
    const f32x4 a1 = lr0[64 + lane];
    const f32x4 b0 = lr1[lane];
    const f32x4 b1 = lr1[64 + lane];
    const f32x4 f0 = frow[lane];
    const f32x4 f1 = frow[64 + lane];

    float eA[8], eB[8];
    eA[0] = __builtin_amdgcn_exp2f(a0.x * f0.x);
    eA[1] = __builtin_amdgcn_exp2f(a0.y * f0.y);
    eA[2] = __builtin_amdgcn_exp2f(a0.z * f0.z);
    eA[3] = __builtin_amdgcn_exp2f(a0.w * f0.w);
    eA[4] = __builtin_amdgcn_exp2f(a1.x * f1.x);
    eA[5] = __builtin_amdgcn_exp2f(a1.y * f1.y);
    eA[6] = __builtin_amdgcn_exp2f(a1.z * f1.z);
    eA[7] = __builtin_amdgcn_exp2f(a1.w * f1.w);
    eB[0] = __builtin_amdgcn_exp2f(b0.x * f0.x);
    eB[1] = __builtin_amdgcn_exp2f(b0.y * f0.y);
    eB[2] = __builtin_amdgcn_exp2f(b0.z * f0.z);
    eB[3] = __builtin_amdgcn_exp2f(b0.w * f0.w);
    eB[4] = __builtin_amdgcn_exp2f(b1.x * f1.x);
    eB[5] = __builtin_amdgcn_exp2f(b1.y * f1.y);
    eB[6] = __builtin_amdgcn_exp2f(b1.z * f1.z);
    eB[7] = __builtin_amdgcn_exp2f(b1.w * f1.w);

    float sA = ((eA[0]+eA[1]) + (eA[2]+eA[3])) + ((eA[4]+eA[5]) + (eA[6]+eA[7]));
    float sB = ((eB[0]+eB[1]) + (eB[2]+eB[3])) + ((eB[4]+eB[5]) + (eB[6]+eB[7]));
    // two independent reduce chains, interleaved for ILP
#pragma unroll
    for (int off = 32; off > 0; off >>= 1) {
        sA += __shfl_xor(sA, off, 64);
        sB += __shfl_xor(sB, off, 64);
    }
    const float invA = __builtin_amdgcn_rcpf(sA);
    const float invB = __builtin_amdgcn_rcpf(sB);

    f32x4 oA0, oA1, oB0, oB1;
    oA0.x = eA[0]*invA; oA0.y = eA[1]*invA; oA0.z = eA[2]*invA; oA0.w = eA[3]*invA;
    oA1.x = eA[4]*invA; oA1.y = eA[5]*invA; oA1.z = eA[6]*invA; oA1.w = eA[7]*invA;
    oB0.x = eB[0]*invB; oB0.y = eB[1]*invB; oB0.z = eB[2]*invB; oB0.w = eB[3]*invB;
    oB1.x = eB[4]*invB; oB1.y = eB[5]*invB; oB1.z = eB[6]*invB; oB1.w = eB[7]*invB;

    f32x4* or0 = (f32x4*)(out + row0 * C_DIM);
    f32x4* or1 = (f32x4*)(out + (row0 + 1) * C_DIM);
    or0[lane]      = oA0;
    or0[64 + lane] = oA1;
    or1[lane]      = oB0;
    or1[64 + lane] = oB1;
}

// ---------------------------------------------------------------------------
extern "C" void kernel_launch(void* const* d_in, const int* in_sizes, int n_in,
                              void* d_out, int out_size, void* d_ws, size_t ws_size,
                              hipStream_t stream) {
    const float* logits    = (const float*)d_in[0];   // (B,C)
    const float* features  = (const float*)d_in[1];   // (B,F)
    const float* mean_vecs = (const float*)d_in[2];   // (C,F)
    const float* wparams   = (const float*)d_in[3];   // (C,3)
    float* out = (float*)d_out;
    float* factor2 = (float*)d_ws;                    // C floats of scratch

    // 512 classes, one wave each: 128 blocks x 256 threads.
    openmax_factor_kernel<<<C_DIM / 4, 256, 0, stream>>>(features, mean_vecs,
                                                         wparams, factor2);

    // 16384 rows, two rows per wave: 2048 blocks x 256 threads.
    openmax_softmax_kernel<<<B_DIM / 8, 256, 0, stream>>>(logits, factor2, out);
}